// Round 7
// baseline (247.931 us; speedup 1.0000x reference)
//
#include <hip/hip_runtime.h>

// Policy net fully fused: GRU(64 steps) -> comm-mean -> 8-agent attention -> MLP heads.
// K0: one-time weight->bf16 MFMA-fragment conversion into d_ws.
// K1: PAIR-SPLIT GRU: 2 waves per 16-seq tile, each owns half the gate column
//     tiles (j in {2sub,2sub+1}); h ping-pongs R1<->Hp with one
//     lgkmcnt+s_barrier per step. 4096 waves -> 4 waves/SIMD (trans-pipe
//     saturation; GRU is transcendental-issue-bound at 5 trans/gate-elem,
//     ~16 cy each wave64). LDS 36.4 KB/WG -> 4 WG/CU. Head on wave sub=0.

typedef float f32x4 __attribute__((ext_vector_type(4)));
typedef short bf16x8 __attribute__((ext_vector_type(8)));

#define MFMA16 __builtin_amdgcn_mfma_f32_16x16x32_bf16
#define LOG2E 1.44269504088896f
#define INV_SQRT_D 0.09449111825230679f

__device__ __forceinline__ short f2bf(float f) {          // RNE (cold paths)
    union { float f; unsigned u; } v; v.f = f;
    unsigned r = v.u + 0x7fffu + ((v.u >> 16) & 1u);
    return (short)(r >> 16);
}
__device__ __forceinline__ short f2bf_hu(float f) {       // round-half-up (hot paths)
    union { float f; unsigned u; } v; v.f = f;
    return (short)((v.u + 0x8000u) >> 16);
}
__device__ __forceinline__ float fexp2(float x) { return __builtin_amdgcn_exp2f(x); }
__device__ __forceinline__ float frcp(float x)  { return __builtin_amdgcn_rcpf(x); }
__device__ __forceinline__ void lds_fence() {             // wave-local LDS RAW guard
    __asm__ __volatile__("s_waitcnt lgkmcnt(0)" ::: "memory");
}
__device__ __forceinline__ void step_barrier() {          // LDS-only barrier (vmcnt stays in flight)
    __asm__ __volatile__("s_waitcnt lgkmcnt(0)\n\ts_barrier" ::: "memory");
}
__device__ __forceinline__ int launder(int x) {           // block LICM/CSE on x
    __asm__ __volatile__("" : "+v"(x));
    return x;
}

// ---------------------------------------------------------------------------
// Kernel 0: head weights -> bf16 B-fragments (MFMA lane layout).
// fid: 0..5 Wm | 6..33 Wq | 34..61 Wk | 62..89 Wv | 90..121 W1 | 122..153 W2 |
//      154..157 heads.  Storage: wf[(fid*64+lane)*8 .. +7]
// ---------------------------------------------------------------------------
__global__ void conv_kernel(
    const float* __restrict__ Wm, const float* __restrict__ Wq,
    const float* __restrict__ Wk, const float* __restrict__ Wv,
    const float* __restrict__ W1, const float* __restrict__ W2,
    const float* __restrict__ Wmean, const float* __restrict__ Wval,
    unsigned short* __restrict__ wf)
{
    int gid = blockIdx.x * 256 + threadIdx.x;
    if (gid >= 158 * 64) return;
    int fid = gid >> 6, lane = gid & 63;
    int l15 = lane & 15, q = lane >> 4;

    short out[8] = {0,0,0,0,0,0,0,0};
    if (fid < 154) {
        const float* W; int nrows, Klim, idx;
        if (fid < 6)        { W = Wm; nrows = 32;  Klim = 80;  idx = fid;       }
        else if (fid < 34)  { W = Wq; nrows = 112; Klim = 112; idx = fid - 6;   }
        else if (fid < 62)  { W = Wk; nrows = 112; Klim = 112; idx = fid - 34;  }
        else if (fid < 90)  { W = Wv; nrows = 112; Klim = 112; idx = fid - 62;  }
        else if (fid < 122) { W = W1; nrows = 128; Klim = 112; idx = fid - 90;  }
        else                { W = W2; nrows = 128; Klim = 128; idx = fid - 122; }
        int nch = (fid < 6) ? 3 : 4;
        int ct = idx / nch, ch = idx - ct * nch;
        int g = ct * 16 + l15, k0 = ch * 32 + q * 8;
        if (g < nrows && (k0 + 8) <= Klim) {
            const float* wp = W + (size_t)g * Klim + k0;
            #pragma unroll
            for (int u = 0; u < 8; ++u) out[u] = f2bf(wp[u]);
        }
    } else {
        int ch = fid - 154, k0 = ch * 32 + q * 8;
        const float* wp = (l15 == 0) ? Wmean : (l15 == 1) ? (Wmean + 128)
                          : (l15 == 2) ? Wval : nullptr;
        if (wp) {
            #pragma unroll
            for (int u = 0; u < 8; ++u) out[u] = f2bf(wp[k0 + u]);
        }
    }
    *(bf16x8*)(wf + ((size_t)fid * 64 + lane) * 8) = *(bf16x8*)out;
}

// ---------------------------------------------------------------------------
// Kernel 1: fused policy. grid 1024 x 256 -> 4096 waves; 2 waves per tile.
// ---------------------------------------------------------------------------
__global__ __launch_bounds__(256, 4)
void policy_kernel(
    const float* __restrict__ seq,    // [32768][64][4]
    const float* __restrict__ W_ih, const float* __restrict__ W_hh,
    const float* __restrict__ b_ih, const float* __restrict__ b_hh,
    const float* __restrict__ embed,
    const unsigned short* __restrict__ wf,
    const float* __restrict__ bm, const float* __restrict__ bq,
    const float* __restrict__ bk, const float* __restrict__ bv,
    const float* __restrict__ b1, const float* __restrict__ b2,
    const float* __restrict__ bmean, const float* __restrict__ bval,
    float* __restrict__ out)          // mean [32768][2] then val [32768]
{
    __shared__ short R1s[2][16][136];  // h(even-phase)|id|c|pad -> O
    __shared__ short Hps[2][16][72];   // h odd-phase ping-pong
    __shared__ short R2s[2][16][136];  // Q -> V^T -> h3
    __shared__ short R3s[2][16][136];  // K -> h4
    __shared__ short Pbs[2][16][40];   // attention probs (A-layout rows)
    __shared__ short C2sm[12][16][8];  // GRU chunk-2 frags, q0-rows only (3 KB)

    const int tid  = threadIdx.x;
    const int wv   = tid >> 6;
    const int lane = tid & 63;
    const int l15  = lane & 15;
    const int q    = lane >> 4;
    const int p    = wv >> 1;          // pair (tile) index within WG
    const int sub  = wv & 1;           // which half of gate tiles this wave owns
    const int sub2 = sub * 2;
    const int seqbase = (blockIdx.x * 2 + p) * 16;   // 16 seqs = 2 batches

    short (*R1)[136] = R1s[p];
    short (*Hp)[72]  = Hps[p];
    short (*R2)[136] = R2s[p];
    short (*R3)[136] = R3s[p];
    short (*Pb)[40]  = Pbs[p];
    const short* C2base = &C2sm[0][0][0];
    const f32x4 zz = {0.f, 0.f, 0.f, 0.f};

    const float sc_rz = -LOG2E;
    const float sc_n  = 2.0f * LOG2E;

    {   // zero tile LDS (both waves of the pair split the work)
        int* z;
        z = (int*)&R1[0][0]; for (int i = lane + 64 * sub; i < 1088; i += 128) z[i] = 0;
        z = (int*)&R2[0][0]; for (int i = lane + 64 * sub; i < 1088; i += 128) z[i] = 0;
        z = (int*)&R3[0][0]; for (int i = lane + 64 * sub; i < 1088; i += 128) z[i] = 0;
        z = (int*)&Pb[0][0]; for (int i = lane + 64 * sub; i < 320;  i += 128) z[i] = 0;
    }
    if (sub == 0) {   // id embedding -> R1 cols 64..79 (agent row i uses embed[i&7])
        int row = lane >> 2, j0 = (lane & 3) * 4;
        f32x4 e = *(const f32x4*)(embed + (row & 7) * 16 + j0);
        #pragma unroll
        for (int u = 0; u < 4; ++u) R1[row][64 + j0 + u] = f2bf(e[u]);
    }
    if (tid < 192) {  // C2 table: x-proj + bias frags, one row per (gate-tile j, l15)
        int j = tid >> 4, l = tid & 15, g = j * 16 + l;
        float s = (j < 8) ? sc_rz : sc_n;
        short f[8] = {0,0,0,0,0,0,0,0};
        #pragma unroll
        for (int u = 0; u < 4; ++u) f[u] = f2bf(W_ih[g * 4 + u] * s);
        f[4] = f2bf(((j < 8) ? (b_ih[g] + b_hh[g]) : b_ih[g]) * s);
        *(bf16x8*)&C2sm[j][l][0] = *(bf16x8*)f;
    }

    // ---- this wave's W_hh fragments: gate tiles j in {sub2, sub2+1} ----
    bf16x8 Bhr[2][2], Bhz[2][2], Bhn[2][2];
    float bhh2[2];
    #pragma unroll
    for (int jj = 0; jj < 2; ++jj) {
        int j = sub2 + jj;
        #pragma unroll
        for (int c = 0; c < 2; ++c) {
            const float* wr = W_hh + (j * 16 + l15) * 64 + c * 32 + q * 8;
            const float* wz = W_hh + ((4 + j) * 16 + l15) * 64 + c * 32 + q * 8;
            const float* wn = W_hh + ((8 + j) * 16 + l15) * 64 + c * 32 + q * 8;
            bf16x8 fr, fz, fn;
            #pragma unroll
            for (int u = 0; u < 8; ++u) {
                fr[u] = f2bf(wr[u] * sc_rz);
                fz[u] = f2bf(wz[u] * sc_rz);
                fn[u] = f2bf(wn[u] * sc_n);
            }
            Bhr[jj][c] = fr; Bhz[jj][c] = fz; Bhn[jj][c] = fn;
        }
        bhh2[jj] = b_hh[128 + j * 16 + l15] * sc_n;
    }

    __syncthreads();   // LDS init + C2 visible to all waves

    // ---- GRU main loop: even t reads R1 writes Hp; odd t reads Hp writes R1 ----
    const short onebf = 0x3f80;
    float h[2][4];
    #pragma unroll
    for (int jj = 0; jj < 2; ++jj)
        #pragma unroll
        for (int r = 0; r < 4; ++r) h[jj][r] = 0.f;

    const float* myseq = seq + (size_t)(seqbase + l15) * 256;

#define GSTEP(HC, CS, HN, NS, XV)                                              \
    do {                                                                       \
        bf16x8 A0 = *(const bf16x8*)((HC) + l15 * (CS) + q * 8);               \
        bf16x8 A1 = *(const bf16x8*)((HC) + l15 * (CS) + 32 + q * 8);          \
        bf16x8 A2;                                                             \
        if (q == 0) {                                                          \
            A2[0] = f2bf_hu((XV)[0]); A2[1] = f2bf_hu((XV)[1]);                \
            A2[2] = f2bf_hu((XV)[2]); A2[3] = f2bf_hu((XV)[3]);                \
            A2[4] = onebf; A2[5] = 0; A2[6] = 0; A2[7] = 0;                    \
        } else {                                                               \
            A2[0]=0;A2[1]=0;A2[2]=0;A2[3]=0;A2[4]=0;A2[5]=0;A2[6]=0;A2[7]=0;   \
        }                                                                      \
        _Pragma("unroll")                                                      \
        for (int jj = 0; jj < 2; ++jj) {                                       \
            int j = sub2 + jj;                                                 \
            bf16x8 c2r = *(const bf16x8*)(C2base + launder(((j)      * 16 + l15) * 8)); \
            bf16x8 c2z = *(const bf16x8*)(C2base + launder(((4 + j)  * 16 + l15) * 8)); \
            bf16x8 c2x = *(const bf16x8*)(C2base + launder(((8 + j)  * 16 + l15) * 8)); \
            f32x4 ar = MFMA16(A2, c2r, zz, 0, 0, 0);                           \
            ar = MFMA16(A0, Bhr[jj][0], ar, 0, 0, 0);                          \
            ar = MFMA16(A1, Bhr[jj][1], ar, 0, 0, 0);                          \
            f32x4 az = MFMA16(A2, c2z, zz, 0, 0, 0);                           \
            az = MFMA16(A0, Bhz[jj][0], az, 0, 0, 0);                          \
            az = MFMA16(A1, Bhz[jj][1], az, 0, 0, 0);                          \
            f32x4 an = MFMA16(A0, Bhn[jj][0], zz, 0, 0, 0);                    \
            an = MFMA16(A1, Bhn[jj][1], an, 0, 0, 0);                          \
            f32x4 ax = MFMA16(A2, c2x, zz, 0, 0, 0);                           \
            _Pragma("unroll")                                                  \
            for (int r = 0; r < 4; ++r) {                                      \
                float e_r  = fexp2(ar[r]);                                     \
                float rg   = frcp(1.f + e_r);                                  \
                float e_z  = fexp2(az[r]);                                     \
                float anb  = an[r] + bhh2[jj];                                 \
                float npre = fmaf(rg, anb, ax[r]);                             \
                float e_t  = fexp2(npre);                                      \
                float tp   = e_t + 1.f;                                        \
                float tm   = e_t - 1.f;                                        \
                float hv   = h[jj][r];                                         \
                float num  = fmaf(hv, tp, e_z * tm);                           \
                float den  = fmaf(tp, e_z, tp);                                \
                float hnew = num * frcp(den);                                  \
                h[jj][r] = hnew;                                               \
                (HN)[(q * 4 + r) * (NS) + 16 * j + l15] = f2bf_hu(hnew);       \
            }                                                                  \
            __builtin_amdgcn_sched_barrier(0);                                 \
        }                                                                      \
    } while (0)

    f32x4 xc = *(const f32x4*)myseq;
    #pragma unroll 1
    for (int kk = 0; kk < 32; ++kk) {
        int t = 2 * kk;
        f32x4 xa = *(const f32x4*)(myseq + (t + 1) * 4);
        GSTEP(&R1[0][0], 136, &Hp[0][0], 72, xc);
        step_barrier();
        int t2 = (t + 2 < 64) ? t + 2 : 63;
        f32x4 xb = *(const f32x4*)(myseq + t2 * 4);
        GSTEP(&Hp[0][0], 72, &R1[0][0], 136, xa);
        step_barrier();
        xc = xb;
    }
#undef GSTEP

    // ---- head phases: wave sub=0 of each pair, wave-local ----
    if (sub != 0) return;

    auto ld = [&](int fid) -> bf16x8 {
        return *(const bf16x8*)(wf + ((size_t)fid * 64 + lane) * 8);
    };

    // P1+P2: msgs = [h|id] @ Wm^T ; comm mean over own batch; c -> R1 cols 80..111
    #pragma unroll
    for (int ct = 0; ct < 2; ++ct) {
        f32x4 acc = zz;
        #pragma unroll
        for (int ch = 0; ch < 3; ++ch) {
            bf16x8 a = *(const bf16x8*)&R1[l15][ch * 32 + q * 8];
            acc = MFMA16(a, ld(ct * 3 + ch), acc, 0, 0, 0);
        }
        float s = acc[0] + acc[1] + acc[2] + acc[3];   // rows q*4..q*4+3
        s += __shfl_xor(s, 16, 64);                    // + other q of same batch
        float cv = 0.125f * s + bm[16 * ct + l15];
        short cb = f2bf_hu(cv);
        #pragma unroll
        for (int r = 0; r < 4; ++r) R1[q * 4 + r][80 + 16 * ct + l15] = cb;
    }
    lds_fence();

    // P3: Q -> R2, K -> R3 (K=112 pad 128); Q pre-scaled by 1/sqrt(112)
    #pragma unroll
    for (int ct = 0; ct < 7; ++ct) {
        f32x4 aq = zz, ak = zz;
        #pragma unroll
        for (int ch = 0; ch < 4; ++ch) {
            bf16x8 a = *(const bf16x8*)&R1[l15][ch * 32 + q * 8];
            aq = MFMA16(a, ld(6  + ct * 4 + ch), aq, 0, 0, 0);
            ak = MFMA16(a, ld(34 + ct * 4 + ch), ak, 0, 0, 0);
        }
        int col = 16 * ct + l15;
        float biq = bq[col], bik = bk[col];
        #pragma unroll
        for (int r = 0; r < 4; ++r) {
            int row = q * 4 + r;
            R2[row][col] = f2bf_hu((aq[r] + biq) * INV_SQRT_D);
            R3[row][col] = f2bf_hu(ak[r] + bik);
        }
    }
    lds_fence();

    // P4: S = Q K^T (16x16 = 2 batches block-diagonal); 8-wide softmax via shfl
    {
        f32x4 acc = zz;
        #pragma unroll
        for (int ch = 0; ch < 4; ++ch) {
            bf16x8 a = *(const bf16x8*)&R2[l15][ch * 32 + q * 8];
            bf16x8 b = *(const bf16x8*)&R3[l15][ch * 32 + q * 8];
            acc = MFMA16(a, b, acc, 0, 0, 0);
        }
        bool collow = (l15 < 8);
        #pragma unroll
        for (int r = 0; r < 4; ++r) {
            int rl = q * 4 + r;
            bool valid = ((rl < 8) == collow);
            float v = acc[r];
            float m = v;
            m = fmaxf(m, __shfl_xor(m, 1, 64));
            m = fmaxf(m, __shfl_xor(m, 2, 64));
            m = fmaxf(m, __shfl_xor(m, 4, 64));
            float e = fexp2(LOG2E * (v - m));
            float s = e;
            s += __shfl_xor(s, 1, 64);
            s += __shfl_xor(s, 2, 64);
            s += __shfl_xor(s, 4, 64);
            float pv = valid ? e * frcp(s) : 0.f;
            Pb[rl][l15] = f2bf_hu(pv);
        }
    }
    lds_fence();

    // P5a: V-pass (hcat in R1 still live) -> V^T overlay in R2 [112][18] (Q dead)
    {
        short* VtR = &R2[0][0];
        #pragma unroll
        for (int ct = 0; ct < 7; ++ct) {
            f32x4 av = zz;
            #pragma unroll
            for (int ch = 0; ch < 4; ++ch) {
                bf16x8 a = *(const bf16x8*)&R1[l15][ch * 32 + q * 8];
                av = MFMA16(a, ld(62 + ct * 4 + ch), av, 0, 0, 0);
            }
            int col = 16 * ct + l15;
            float biv = bv[col];
            #pragma unroll
            for (int r = 0; r < 4; ++r)
                VtR[col * 18 + q * 4 + r] = f2bf_hu(av[r] + biv);
        }
    }
    lds_fence();

    // P5b: O = P V (K=32; Pb cols 16..31 zero) -> R1
    {
        const short* VtR = &R2[0][0];
        bf16x8 a = *(const bf16x8*)&Pb[l15][q * 8];
        #pragma unroll
        for (int ct = 0; ct < 7; ++ct) {
            bf16x8 b = *(const bf16x8*)(VtR + (16 * ct + l15) * 18 + q * 8);
            f32x4 acc = MFMA16(a, b, zz, 0, 0, 0);
            #pragma unroll
            for (int r = 0; r < 4; ++r) R1[q * 4 + r][16 * ct + l15] = f2bf_hu(acc[r]);
        }
    }
    lds_fence();

    // P6: h3 = relu(O @ W1^T + b1)  K=112 pad 128 -> R2 (Vt dead; all 128 cols written)
    #pragma unroll
    for (int ct = 0; ct < 8; ++ct) {
        f32x4 acc = zz;
        #pragma unroll
        for (int ch = 0; ch < 4; ++ch) {
            bf16x8 a = *(const bf16x8*)&R1[l15][ch * 32 + q * 8];
            acc = MFMA16(a, ld(90 + ct * 4 + ch), acc, 0, 0, 0);
        }
        float bias = b1[16 * ct + l15];
        #pragma unroll
        for (int r = 0; r < 4; ++r)
            R2[q * 4 + r][16 * ct + l15] = f2bf_hu(fmaxf(acc[r] + bias, 0.f));
    }
    lds_fence();

    // P7: h4 = relu(h3 @ W2^T + b2)  K=128 -> R3
    #pragma unroll
    for (int ct = 0; ct < 8; ++ct) {
        f32x4 acc = zz;
        #pragma unroll
        for (int ch = 0; ch < 4; ++ch) {
            bf16x8 a = *(const bf16x8*)&R2[l15][ch * 32 + q * 8];
            acc = MFMA16(a, ld(122 + ct * 4 + ch), acc, 0, 0, 0);
        }
        float bias = b2[16 * ct + l15];
        #pragma unroll
        for (int r = 0; r < 4; ++r)
            R3[q * 4 + r][16 * ct + l15] = f2bf_hu(fmaxf(acc[r] + bias, 0.f));
    }
    lds_fence();

    // P8: heads (K=128): cols 0,1 -> mean; col 2 -> value
    {
        f32x4 acc = zz;
        #pragma unroll
        for (int ch = 0; ch < 4; ++ch) {
            bf16x8 a = *(const bf16x8*)&R3[l15][ch * 32 + q * 8];
            acc = MFMA16(a, ld(154 + ch), acc, 0, 0, 0);
        }
        if (l15 < 3) {
            float bias = (l15 == 0) ? bmean[0] : (l15 == 1) ? bmean[1] : bval[0];
            #pragma unroll
            for (int r = 0; r < 4; ++r) {
                int A = seqbase + q * 4 + r;
                float v = acc[r] + bias;
                if (l15 < 2) out[(size_t)A * 2 + l15] = v;
                else         out[65536 + A] = v;
            }
        }
    }
}

// ---------------------------------------------------------------------------
extern "C" void kernel_launch(void* const* d_in, const int* in_sizes, int n_in,
                              void* d_out, int out_size, void* d_ws, size_t ws_size,
                              hipStream_t stream) {
    const float* seq   = (const float*)d_in[0];
    const float* W_ih  = (const float*)d_in[1];
    const float* W_hh  = (const float*)d_in[2];
    const float* b_ih  = (const float*)d_in[3];
    const float* b_hh  = (const float*)d_in[4];
    const float* embed = (const float*)d_in[5];
    const float* Wm    = (const float*)d_in[6];
    const float* bm    = (const float*)d_in[7];
    const float* Wq    = (const float*)d_in[8];
    const float* bq    = (const float*)d_in[9];
    const float* Wk    = (const float*)d_in[10];
    const float* bk    = (const float*)d_in[11];
    const float* Wv    = (const float*)d_in[12];
    const float* bv    = (const float*)d_in[13];
    const float* W1    = (const float*)d_in[14];
    const float* b1    = (const float*)d_in[15];
    const float* W2    = (const float*)d_in[16];
    const float* b2    = (const float*)d_in[17];
    const float* Wmean = (const float*)d_in[18];
    const float* bmean = (const float*)d_in[19];
    const float* Wval  = (const float*)d_in[20];
    const float* bval  = (const float*)d_in[21];

    unsigned short* wf = (unsigned short*)d_ws;   // 158 frags * 64 lanes * 16 B

    conv_kernel<<<40, 256, 0, stream>>>(Wm, Wq, Wk, Wv, W1, W2, Wmean, Wval, wf);
    policy_kernel<<<1024, 256, 0, stream>>>(seq, W_ih, W_hh, b_ih, b_hh, embed, wf,
                                            bm, bq, bk, bv, b1, b2, bmean, bval,
                                            (float*)d_out);
}

// Round 9
// 243.830 us; speedup vs baseline: 1.0168x; 1.0168x over previous
//
#include <hip/hip_runtime.h>

// Policy net fully fused: GRU(64 steps) -> comm-mean -> 8-agent attention -> MLP heads.
// K0: one-time weight->bf16 MFMA-fragment conversion into d_ws (head weights).
// K1: h^T GRU: one wave = 16 seqs; gates^T = W_tile @ [x;1;h] with seqs in MFMA
//     columns. h state lives in packed registers; step-to-step layout fix
//     (C-layout rows -> B-layout k) = 16 FULL-EXEC ds_bpermute + 8 cndmask.
//     R8 BUG FIXED: ternary around convergent ds_bpermute created divergent
//     branches -> half-EXEC bpermute -> garbage pulls. Now: all pulls issued
//     unconditionally, results selected with int cndmask.
//     W frags in 40 KB WG-shared LDS (laundered reads beat the spill trap:
//     usable regs/wave = 256 / waves_per_simd, measured R3-R7).
//     Head phases aliased into the dead W-table LDS after one __syncthreads.

typedef float f32x4 __attribute__((ext_vector_type(4)));
typedef short bf16x8 __attribute__((ext_vector_type(8)));

#define MFMA16 __builtin_amdgcn_mfma_f32_16x16x32_bf16
#define LOG2E 1.44269504088896f
#define INV_SQRT_D 0.09449111825230679f

__device__ __forceinline__ short f2bf(float f) {          // RNE (cold paths)
    union { float f; unsigned u; } v; v.f = f;
    unsigned r = v.u + 0x7fffu + ((v.u >> 16) & 1u);
    return (short)(r >> 16);
}
__device__ __forceinline__ short f2bf_hu(float f) {       // round-half-up (hot paths)
    union { float f; unsigned u; } v; v.f = f;
    return (short)((v.u + 0x8000u) >> 16);
}
__device__ __forceinline__ unsigned packbf(float a, float b) {  // bf16(a) | bf16(b)<<16
    union { float f; unsigned u; } x, y; x.f = a; y.f = b;
    return ((y.u + 0x8000u) & 0xffff0000u) | ((x.u + 0x8000u) >> 16);
}
__device__ __forceinline__ float fexp2(float x) { return __builtin_amdgcn_exp2f(x); }
__device__ __forceinline__ float frcp(float x)  { return __builtin_amdgcn_rcpf(x); }
__device__ __forceinline__ void lds_fence() {             // wave-local LDS RAW guard
    __asm__ __volatile__("s_waitcnt lgkmcnt(0)" ::: "memory");
}
__device__ __forceinline__ int launder(int x) {           // block LICM/CSE on x
    __asm__ __volatile__("" : "+v"(x));
    return x;
}

union i4h8 { int i[4]; bf16x8 h; };

// ---------------------------------------------------------------------------
// Kernel 0: head weights -> bf16 B-fragments (MFMA lane layout).
// fid: 0..5 Wm | 6..33 Wq | 34..61 Wk | 62..89 Wv | 90..121 W1 | 122..153 W2 |
//      154..157 heads.  Storage: wf[(fid*64+lane)*8 .. +7]
// ---------------------------------------------------------------------------
__global__ void conv_kernel(
    const float* __restrict__ Wm, const float* __restrict__ Wq,
    const float* __restrict__ Wk, const float* __restrict__ Wv,
    const float* __restrict__ W1, const float* __restrict__ W2,
    const float* __restrict__ Wmean, const float* __restrict__ Wval,
    unsigned short* __restrict__ wf)
{
    int gid = blockIdx.x * 256 + threadIdx.x;
    if (gid >= 158 * 64) return;
    int fid = gid >> 6, lane = gid & 63;
    int l15 = lane & 15, q = lane >> 4;

    short out[8] = {0,0,0,0,0,0,0,0};
    if (fid < 154) {
        const float* W; int nrows, Klim, idx;
        if (fid < 6)        { W = Wm; nrows = 32;  Klim = 80;  idx = fid;       }
        else if (fid < 34)  { W = Wq; nrows = 112; Klim = 112; idx = fid - 6;   }
        else if (fid < 62)  { W = Wk; nrows = 112; Klim = 112; idx = fid - 34;  }
        else if (fid < 90)  { W = Wv; nrows = 112; Klim = 112; idx = fid - 62;  }
        else if (fid < 122) { W = W1; nrows = 128; Klim = 112; idx = fid - 90;  }
        else                { W = W2; nrows = 128; Klim = 128; idx = fid - 122; }
        int nch = (fid < 6) ? 3 : 4;
        int ct = idx / nch, ch = idx - ct * nch;
        int g = ct * 16 + l15, k0 = ch * 32 + q * 8;
        if (g < nrows && (k0 + 8) <= Klim) {
            const float* wp = W + (size_t)g * Klim + k0;
            #pragma unroll
            for (int u = 0; u < 8; ++u) out[u] = f2bf(wp[u]);
        }
    } else {
        int ch = fid - 154, k0 = ch * 32 + q * 8;
        const float* wp = (l15 == 0) ? Wmean : (l15 == 1) ? (Wmean + 128)
                          : (l15 == 2) ? Wval : nullptr;
        if (wp) {
            #pragma unroll
            for (int u = 0; u < 8; ++u) out[u] = f2bf(wp[k0 + u]);
        }
    }
    *(bf16x8*)(wf + ((size_t)fid * 64 + lane) * 8) = *(bf16x8*)out;
}

// ---------------------------------------------------------------------------
// Kernel 1: fused policy. grid 512 x 256 -> 2048 waves x 16 seqs.
// LDS union (57344 B):
//   GRU phase: frag table, frag f at U[f*512 + lane*8], f=0..39:
//     f=0..23  W_hh A-frags (tile jg = f>>1, chunk c = f&1), pre-scaled
//     f=24..35 W_ih A-frags + bias col k=4 (r,z: b_ih+b_hh; n: b_ih)
//     f=36..39 n-gate b_hh bias frags (k=5 column)
//   Head phase (after __syncthreads): per-tile (=wave wv) at U + wv*7168:
//     R1[16][136] @0 | R2[16][136] @2176 | R3[16][136] @4352 | Pb[16][40] @6528
// ---------------------------------------------------------------------------
__global__ __launch_bounds__(256, 2)
void policy_kernel(
    const float* __restrict__ seq,    // [32768][64][4]
    const float* __restrict__ W_ih, const float* __restrict__ W_hh,
    const float* __restrict__ b_ih, const float* __restrict__ b_hh,
    const float* __restrict__ embed,
    const unsigned short* __restrict__ wf,
    const float* __restrict__ bm, const float* __restrict__ bq,
    const float* __restrict__ bk, const float* __restrict__ bv,
    const float* __restrict__ b1, const float* __restrict__ b2,
    const float* __restrict__ bmean, const float* __restrict__ bval,
    float* __restrict__ out)          // mean [32768][2] then val [32768]
{
    __shared__ __align__(16) short U[28672];

    const int tid  = threadIdx.x;
    const int wv   = tid >> 6;
    const int lane = tid & 63;
    const int l15  = lane & 15;
    const int q    = lane >> 4;
    const int seqbase = (blockIdx.x * 4 + wv) * 16;   // 16 seqs = 2 batches
    const f32x4 zz = {0.f, 0.f, 0.f, 0.f};

    const float sc_rz = -LOG2E;
    const float sc_n  = 2.0f * LOG2E;

    // ---- cooperative GRU frag-table fill (2560 lane-rows / 256 threads) ----
    for (int it = 0; it < 10; ++it) {
        int row = it * 256 + tid;          // 0..2559
        int f = row >> 6, ln = row & 63;
        int l = ln & 15, qq = ln >> 4;
        short v[8] = {0,0,0,0,0,0,0,0};
        if (f < 24) {                      // W_hh A-frag: A[m=l][k=c*32+qq*8+u]
            int jg = f >> 1, c = f & 1;
            float s = (jg < 8) ? sc_rz : sc_n;
            const float* wp = W_hh + (jg * 16 + l) * 64 + c * 32 + qq * 8;
            #pragma unroll
            for (int u = 0; u < 8; ++u) v[u] = f2bf(wp[u] * s);
        } else if (f < 36) {               // W_ih + bias(k=4)
            int jx = f - 24;
            if (qq == 0) {
                float s = (jx < 8) ? sc_rz : sc_n;
                int g = jx * 16 + l;
                #pragma unroll
                for (int u = 0; u < 4; ++u) v[u] = f2bf(W_ih[g * 4 + u] * s);
                v[4] = f2bf(((jx < 8) ? (b_ih[g] + b_hh[g]) : b_ih[g]) * s);
            }
        } else {                           // b_hh_n bias (k=5)
            int jn = f - 36;
            if (qq == 0) v[5] = f2bf(b_hh[128 + jn * 16 + l] * sc_n);
        }
        *(bf16x8*)&U[row * 8] = *(bf16x8*)v;
    }
    __syncthreads();

    // ---- GRU main loop: h^T in packed registers ----
    // Lane (l15,q): h[jt][r] = h-dim (jt*16 + q*4 + r) of seq l15.
    // Ph[jt][w] = pack(h[2w], h[2w+1]).
    unsigned Ph[4][2] = {{0u,0u},{0u,0u},{0u,0u},{0u,0u}};
    float h[4][4];
    #pragma unroll
    for (int jt = 0; jt < 4; ++jt)
        #pragma unroll
        for (int r = 0; r < 4; ++r) h[jt][r] = 0.f;

    const int srcA = (((lane >> 4) & 1) * 32 + l15) * 4;   // bpermute byte addr
    const int srcB = srcA + 64;
    const bool qlow = (q < 2);
    const float* myseq = seq + (size_t)(seqbase + l15) * 256;

#define LDW(f) (*(const bf16x8*)(Wb + (f) * 512))
#define BP(a, v) __builtin_amdgcn_ds_bpermute((a), (int)(v))

    // FULL-EXEC pull of one h chunk: consumers q<2 take Plo, q>=2 take Phi.
    // All 8 bpermutes execute unconditionally (convergent); selects are cndmask.
    auto pull = [&](const unsigned* Plo, const unsigned* Phi) -> bf16x8 {
        int aL0 = BP(srcA, Plo[0]), aL1 = BP(srcA, Plo[1]);
        int bL0 = BP(srcB, Plo[0]), bL1 = BP(srcB, Plo[1]);
        int aH0 = BP(srcA, Phi[0]), aH1 = BP(srcA, Phi[1]);
        int bH0 = BP(srcB, Phi[0]), bH1 = BP(srcB, Phi[1]);
        i4h8 u;
        u.i[0] = qlow ? aL0 : aH0;
        u.i[1] = qlow ? aL1 : aH1;
        u.i[2] = qlow ? bL0 : bH0;
        u.i[3] = qlow ? bL1 : bH1;
        return u.h;
    };

    f32x4 xc = *(const f32x4*)myseq;

    for (int t = 0; t < 64; ++t) {
        int tn = (t < 63) ? t + 1 : 63;
        f32x4 xnext = *(const f32x4*)(myseq + tn * 4);

        const short* Wb = U + launder(lane * 8);   // re-laundered per step: blocks LICM

        // x B-frag: k0..3 = x, k4=k5=1.0 (bias cols), q!=0 lanes zero
        i4h8 xb;
        unsigned xu0 = packbf(xc[0], xc[1]);
        unsigned xu1 = packbf(xc[2], xc[3]);
        xb.i[0] = (q == 0) ? (int)xu0 : 0;
        xb.i[1] = (q == 0) ? (int)xu1 : 0;
        xb.i[2] = (q == 0) ? 0x3f803f80 : 0;
        xb.i[3] = 0;
        bf16x8 xB = xb.h;

        // h B-frags via full-exec cross-lane pulls
        bf16x8 Bh0 = pull(Ph[0], Ph[1]);   // h dims 0..31
        bf16x8 Bh1 = pull(Ph[2], Ph[3]);   // h dims 32..63

        #pragma unroll
        for (int jt = 0; jt < 4; ++jt) {
            f32x4 ar = MFMA16(LDW(24 + jt), xB, zz, 0, 0, 0);
            ar = MFMA16(LDW(jt * 2),     Bh0, ar, 0, 0, 0);
            ar = MFMA16(LDW(jt * 2 + 1), Bh1, ar, 0, 0, 0);
            f32x4 az = MFMA16(LDW(28 + jt), xB, zz, 0, 0, 0);
            az = MFMA16(LDW((4 + jt) * 2),     Bh0, az, 0, 0, 0);
            az = MFMA16(LDW((4 + jt) * 2 + 1), Bh1, az, 0, 0, 0);
            f32x4 an = MFMA16(LDW(36 + jt), xB, zz, 0, 0, 0);   // b_hh_n via k5
            an = MFMA16(LDW((8 + jt) * 2),     Bh0, an, 0, 0, 0);
            an = MFMA16(LDW((8 + jt) * 2 + 1), Bh1, an, 0, 0, 0);
            f32x4 ax = MFMA16(LDW(32 + jt), xB, zz, 0, 0, 0);

            #pragma unroll
            for (int r = 0; r < 4; ++r) {
                float e_r  = fexp2(ar[r]);                 // exp(-pre_r)
                float rg   = frcp(1.f + e_r);
                float e_z  = fexp2(az[r]);                 // exp(-pre_z)
                float npre = fmaf(rg, an[r], ax[r]);       // 2log2e*(xn + r*hn)
                float e_t  = fexp2(npre);
                float tp   = e_t + 1.f;
                float tm   = e_t - 1.f;
                float hv   = h[jt][r];
                float num  = fmaf(hv, tp, e_z * tm);
                float den  = fmaf(tp, e_z, tp);
                h[jt][r] = num * frcp(den);
            }
            Ph[jt][0] = packbf(h[jt][0], h[jt][1]);
            Ph[jt][1] = packbf(h[jt][2], h[jt][3]);
        }
        xc = xnext;
    }

    // final hcat frags: B[k=dim][n=seq] lane layout == A[m=seq][k=dim]
    bf16x8 Hc0 = pull(Ph[0], Ph[1]);
    bf16x8 Hc1 = pull(Ph[2], Ph[3]);
#undef LDW
#undef BP

    __syncthreads();   // all waves done with the W table; re-purpose LDS

    // ---- head buffers (alias W table) ----
    short (*R1)[136] = (short(*)[136])(U + wv * 7168);
    short (*R2)[136] = (short(*)[136])(U + wv * 7168 + 2176);
    short (*R3)[136] = (short(*)[136])(U + wv * 7168 + 4352);
    short (*Pb)[40]  = (short(*)[40]) (U + wv * 7168 + 6528);

    *(bf16x8*)&R1[l15][q * 8]      = Hc0;   // h cols 0..31
    *(bf16x8*)&R1[l15][32 + q * 8] = Hc1;   // h cols 32..63
    {   // id embedding -> R1 cols 64..79 (agent row i uses embed[i&7])
        const float* ep = embed + (l15 & 7) * 16 + q * 4;
        #pragma unroll
        for (int u = 0; u < 4; ++u) R1[l15][64 + q * 4 + u] = f2bf(ep[u]);
    }
    const bf16x8 z8 = {0,0,0,0,0,0,0,0};
    if (q < 2) {   // zero pad cols 112..127 (K=128 MFMA reads)
        *(bf16x8*)&R1[l15][112 + q * 8] = z8;
        *(bf16x8*)&R2[l15][112 + q * 8] = z8;
        *(bf16x8*)&R3[l15][112 + q * 8] = z8;
    }
    if (q < 3) *(bf16x8*)&Pb[l15][16 + q * 8] = z8;   // zero Pb cols 16..39
    lds_fence();

    auto ld = [&](int fid) -> bf16x8 {
        return *(const bf16x8*)(wf + ((size_t)fid * 64 + lane) * 8);
    };

    // P1+P2: msgs = [h|id] @ Wm^T ; comm mean over own batch; c -> R1 cols 80..111
    #pragma unroll
    for (int ct = 0; ct < 2; ++ct) {
        f32x4 acc = zz;
        #pragma unroll
        for (int ch = 0; ch < 3; ++ch) {
            bf16x8 a = *(const bf16x8*)&R1[l15][ch * 32 + q * 8];
            acc = MFMA16(a, ld(ct * 3 + ch), acc, 0, 0, 0);
        }
        float s = acc[0] + acc[1] + acc[2] + acc[3];   // rows q*4..q*4+3
        s += __shfl_xor(s, 16, 64);                    // + other q of same batch
        float cv = 0.125f * s + bm[16 * ct + l15];
        short cb = f2bf_hu(cv);
        #pragma unroll
        for (int r = 0; r < 4; ++r) R1[q * 4 + r][80 + 16 * ct + l15] = cb;
    }
    lds_fence();

    // P3: Q -> R2, K -> R3 (K=112 pad 128); Q pre-scaled by 1/sqrt(112)
    #pragma unroll
    for (int ct = 0; ct < 7; ++ct) {
        f32x4 aq = zz, ak = zz;
        #pragma unroll
        for (int ch = 0; ch < 4; ++ch) {
            bf16x8 a = *(const bf16x8*)&R1[l15][ch * 32 + q * 8];
            aq = MFMA16(a, ld(6  + ct * 4 + ch), aq, 0, 0, 0);
            ak = MFMA16(a, ld(34 + ct * 4 + ch), ak, 0, 0, 0);
        }
        int col = 16 * ct + l15;
        float biq = bq[col], bik = bk[col];
        #pragma unroll
        for (int r = 0; r < 4; ++r) {
            int row = q * 4 + r;
            R2[row][col] = f2bf_hu((aq[r] + biq) * INV_SQRT_D);
            R3[row][col] = f2bf_hu(ak[r] + bik);
        }
    }
    lds_fence();

    // P4: S = Q K^T (16x16 = 2 batches block-diagonal); 8-wide softmax via shfl
    {
        f32x4 acc = zz;
        #pragma unroll
        for (int ch = 0; ch < 4; ++ch) {
            bf16x8 a = *(const bf16x8*)&R2[l15][ch * 32 + q * 8];
            bf16x8 b = *(const bf16x8*)&R3[l15][ch * 32 + q * 8];
            acc = MFMA16(a, b, acc, 0, 0, 0);
        }
        bool collow = (l15 < 8);
        #pragma unroll
        for (int r = 0; r < 4; ++r) {
            int rl = q * 4 + r;
            bool valid = ((rl < 8) == collow);
            float v = acc[r];
            float m = v;
            m = fmaxf(m, __shfl_xor(m, 1, 64));
            m = fmaxf(m, __shfl_xor(m, 2, 64));
            m = fmaxf(m, __shfl_xor(m, 4, 64));
            float e = fexp2(LOG2E * (v - m));
            float s = e;
            s += __shfl_xor(s, 1, 64);
            s += __shfl_xor(s, 2, 64);
            s += __shfl_xor(s, 4, 64);
            float pv = valid ? e * frcp(s) : 0.f;
            Pb[rl][l15] = f2bf_hu(pv);
        }
    }
    lds_fence();

    // P5a: V-pass (hcat in R1 still live) -> V^T overlay in R2 [112][18] (Q dead)
    {
        short* VtR = &R2[0][0];
        #pragma unroll
        for (int ct = 0; ct < 7; ++ct) {
            f32x4 av = zz;
            #pragma unroll
            for (int ch = 0; ch < 4; ++ch) {
                bf16x8 a = *(const bf16x8*)&R1[l15][ch * 32 + q * 8];
                av = MFMA16(a, ld(62 + ct * 4 + ch), av, 0, 0, 0);
            }
            int col = 16 * ct + l15;
            float biv = bv[col];
            #pragma unroll
            for (int r = 0; r < 4; ++r)
                VtR[col * 18 + q * 4 + r] = f2bf_hu(av[r] + biv);
        }
    }
    lds_fence();

    // P5b: O = P V (K=32; Pb cols 16..31 zero) -> R1
    {
        const short* VtR = &R2[0][0];
        bf16x8 a = *(const bf16x8*)&Pb[l15][q * 8];
        #pragma unroll
        for (int ct = 0; ct < 7; ++ct) {
            bf16x8 b = *(const bf16x8*)(VtR + (16 * ct + l15) * 18 + q * 8);
            f32x4 acc = MFMA16(a, b, zz, 0, 0, 0);
            #pragma unroll
            for (int r = 0; r < 4; ++r) R1[q * 4 + r][16 * ct + l15] = f2bf_hu(acc[r]);
        }
    }
    lds_fence();

    // P6: h3 = relu(O @ W1^T + b1)  K=112 pad 128 -> R2 (Vt dead; all cols written)
    #pragma unroll
    for (int ct = 0; ct < 8; ++ct) {
        f32x4 acc = zz;
        #pragma unroll
        for (int ch = 0; ch < 4; ++ch) {
            bf16x8 a = *(const bf16x8*)&R1[l15][ch * 32 + q * 8];
            acc = MFMA16(a, ld(90 + ct * 4 + ch), acc, 0, 0, 0);
        }
        float bias = b1[16 * ct + l15];
        #pragma unroll
        for (int r = 0; r < 4; ++r)
            R2[q * 4 + r][16 * ct + l15] = f2bf_hu(fmaxf(acc[r] + bias, 0.f));
    }
    lds_fence();

    // P7: h4 = relu(h3 @ W2^T + b2)  K=128 -> R3
    #pragma unroll
    for (int ct = 0; ct < 8; ++ct) {
        f32x4 acc = zz;
        #pragma unroll
        for (int ch = 0; ch < 4; ++ch) {
            bf16x8 a = *(const bf16x8*)&R2[l15][ch * 32 + q * 8];
            acc = MFMA16(a, ld(122 + ct * 4 + ch), acc, 0, 0, 0);
        }
        float bias = b2[16 * ct + l15];
        #pragma unroll
        for (int r = 0; r < 4; ++r)
            R3[q * 4 + r][16 * ct + l15] = f2bf_hu(fmaxf(acc[r] + bias, 0.f));
    }
    lds_fence();

    // P8: heads (K=128): cols 0,1 -> mean; col 2 -> value
    {
        f32x4 acc = zz;
        #pragma unroll
        for (int ch = 0; ch < 4; ++ch) {
            bf16x8 a = *(const bf16x8*)&R3[l15][ch * 32 + q * 8];
            acc = MFMA16(a, ld(154 + ch), acc, 0, 0, 0);
        }
        if (l15 < 3) {
            float bias = (l15 == 0) ? bmean[0] : (l15 == 1) ? bmean[1] : bval[0];
            #pragma unroll
            for (int r = 0; r < 4; ++r) {
                int A = seqbase + q * 4 + r;
                float v = acc[r] + bias;
                if (l15 < 2) out[(size_t)A * 2 + l15] = v;
                else         out[65536 + A] = v;
            }
        }
    }
}

// ---------------------------------------------------------------------------
extern "C" void kernel_launch(void* const* d_in, const int* in_sizes, int n_in,
                              void* d_out, int out_size, void* d_ws, size_t ws_size,
                              hipStream_t stream) {
    const float* seq   = (const float*)d_in[0];
    const float* W_ih  = (const float*)d_in[1];
    const float* W_hh  = (const float*)d_in[2];
    const float* b_ih  = (const float*)d_in[3];
    const float* b_hh  = (const float*)d_in[4];
    const float* embed = (const float*)d_in[5];
    const float* Wm    = (const float*)d_in[6];
    const float* bm    = (const float*)d_in[7];
    const float* Wq    = (const float*)d_in[8];
    const float* bq    = (const float*)d_in[9];
    const float* Wk    = (const float*)d_in[10];
    const float* bk    = (const float*)d_in[11];
    const float* Wv    = (const float*)d_in[12];
    const float* bv    = (const float*)d_in[13];
    const float* W1    = (const float*)d_in[14];
    const float* b1    = (const float*)d_in[15];
    const float* W2    = (const float*)d_in[16];
    const float* b2    = (const float*)d_in[17];
    const float* Wmean = (const float*)d_in[18];
    const float* bmean = (const float*)d_in[19];
    const float* Wval  = (const float*)d_in[20];
    const float* bval  = (const float*)d_in[21];

    unsigned short* wf = (unsigned short*)d_ws;   // 158 frags * 64 lanes * 16 B

    conv_kernel<<<40, 256, 0, stream>>>(Wm, Wq, Wk, Wv, W1, W2, Wmean, Wval, wf);
    policy_kernel<<<512, 256, 0, stream>>>(seq, W_ih, W_hh, b_ih, b_hh, embed, wf,
                                           bm, bq, bk, bv, b1, b2, bmean, bval,
                                           (float*)d_out);
}

// Round 11
// 238.963 us; speedup vs baseline: 1.0375x; 1.0204x over previous
//
#include <hip/hip_runtime.h>

// Policy net fully fused: GRU(64 steps) -> comm-mean -> 8-agent attention -> MLP heads.
// K0: one-time weight->bf16 MFMA-fragment conversion into d_ws (head weights).
// K1: h^T GRU, HYBRID operand placement (R6 x R9 synthesis):
//     - W_hh A-frags (24, dense, 96 regs): REGISTERS
//     - h state: REGISTERS, redistributed per step by 16 full-EXEC ds_bpermute.
//       R8/R10 TRAP: ternary selects on bpermute results get if-converted into
//       divergent branches under register pressure -> half-EXEC bpermute ->
//       garbage. Fix: bitwise mask blend (v_bfi) with a laundered mask —
//       cannot be turned into control flow.
//     - x-proj/bias A-frags (12): LDS, laundered ds_read_b128 per step
//       (hoisting them = +48 regs = spill trap measured R3/R4/R7)
//     - b_hh_n: 16 per-lane f32 consts
//     Per-step LDS: 12 reads + 16 bperm (R9's 40-read table was LDS-pipe bound).
//     Head phases aliased into dead LDS after one __syncthreads.

typedef float f32x4 __attribute__((ext_vector_type(4)));
typedef short bf16x8 __attribute__((ext_vector_type(8)));

#define MFMA16 __builtin_amdgcn_mfma_f32_16x16x32_bf16
#define LOG2E 1.44269504088896f
#define INV_SQRT_D 0.09449111825230679f

__device__ __forceinline__ short f2bf(float f) {          // RNE (cold paths)
    union { float f; unsigned u; } v; v.f = f;
    unsigned r = v.u + 0x7fffu + ((v.u >> 16) & 1u);
    return (short)(r >> 16);
}
__device__ __forceinline__ short f2bf_hu(float f) {       // round-half-up (hot paths)
    union { float f; unsigned u; } v; v.f = f;
    return (short)((v.u + 0x8000u) >> 16);
}
__device__ __forceinline__ unsigned packbf(float a, float b) {  // bf16(a) | bf16(b)<<16
    union { float f; unsigned u; } x, y; x.f = a; y.f = b;
    return ((y.u + 0x8000u) & 0xffff0000u) | ((x.u + 0x8000u) >> 16);
}
__device__ __forceinline__ float fexp2(float x) { return __builtin_amdgcn_exp2f(x); }
__device__ __forceinline__ float frcp(float x)  { return __builtin_amdgcn_rcpf(x); }
__device__ __forceinline__ void lds_fence() {             // wave-local LDS RAW guard
    __asm__ __volatile__("s_waitcnt lgkmcnt(0)" ::: "memory");
}
__device__ __forceinline__ int launder(int x) {           // block LICM/CSE/value-tracking
    __asm__ __volatile__("" : "+v"(x));
    return x;
}

union i4h8 { int i[4]; bf16x8 h; };

// ---------------------------------------------------------------------------
// Kernel 0: head weights -> bf16 B-fragments (MFMA lane layout).
// fid: 0..5 Wm | 6..33 Wq | 34..61 Wk | 62..89 Wv | 90..121 W1 | 122..153 W2 |
//      154..157 heads.  Storage: wf[(fid*64+lane)*8 .. +7]
// ---------------------------------------------------------------------------
__global__ void conv_kernel(
    const float* __restrict__ Wm, const float* __restrict__ Wq,
    const float* __restrict__ Wk, const float* __restrict__ Wv,
    const float* __restrict__ W1, const float* __restrict__ W2,
    const float* __restrict__ Wmean, const float* __restrict__ Wval,
    unsigned short* __restrict__ wf)
{
    int gid = blockIdx.x * 256 + threadIdx.x;
    if (gid >= 158 * 64) return;
    int fid = gid >> 6, lane = gid & 63;
    int l15 = lane & 15, q = lane >> 4;

    short out[8] = {0,0,0,0,0,0,0,0};
    if (fid < 154) {
        const float* W; int nrows, Klim, idx;
        if (fid < 6)        { W = Wm; nrows = 32;  Klim = 80;  idx = fid;       }
        else if (fid < 34)  { W = Wq; nrows = 112; Klim = 112; idx = fid - 6;   }
        else if (fid < 62)  { W = Wk; nrows = 112; Klim = 112; idx = fid - 34;  }
        else if (fid < 90)  { W = Wv; nrows = 112; Klim = 112; idx = fid - 62;  }
        else if (fid < 122) { W = W1; nrows = 128; Klim = 112; idx = fid - 90;  }
        else                { W = W2; nrows = 128; Klim = 128; idx = fid - 122; }
        int nch = (fid < 6) ? 3 : 4;
        int ct = idx / nch, ch = idx - ct * nch;
        int g = ct * 16 + l15, k0 = ch * 32 + q * 8;
        if (g < nrows && (k0 + 8) <= Klim) {
            const float* wp = W + (size_t)g * Klim + k0;
            #pragma unroll
            for (int u = 0; u < 8; ++u) out[u] = f2bf(wp[u]);
        }
    } else {
        int ch = fid - 154, k0 = ch * 32 + q * 8;
        const float* wp = (l15 == 0) ? Wmean : (l15 == 1) ? (Wmean + 128)
                          : (l15 == 2) ? Wval : nullptr;
        if (wp) {
            #pragma unroll
            for (int u = 0; u < 8; ++u) out[u] = f2bf(wp[k0 + u]);
        }
    }
    *(bf16x8*)(wf + ((size_t)fid * 64 + lane) * 8) = *(bf16x8*)out;
}

// ---------------------------------------------------------------------------
// Kernel 1: fused policy. grid 512 x 256 -> 2048 waves x 16 seqs.
// LDS union (57344 B):
//   GRU phase: x-frag table, frag f at U[f*512 + lane*8], f=0..11:
//     rows g=f*16+l15 (f=0..3 r, 4..7 z, 8..11 n), only q0 lanes:
//     k0..3 = W_ih*scale, k4 = bias*scale (r,z: b_ih+b_hh; n: b_ih)
//   Head phase (after __syncthreads): per-tile (=wave wv) at U + wv*7168 shorts:
//     R1[16][136] | R2[16][136] | R3[16][136] | Pb[16][40]
// ---------------------------------------------------------------------------
__global__ __launch_bounds__(256, 2)
void policy_kernel(
    const float* __restrict__ seq,    // [32768][64][4]
    const float* __restrict__ W_ih, const float* __restrict__ W_hh,
    const float* __restrict__ b_ih, const float* __restrict__ b_hh,
    const float* __restrict__ embed,
    const unsigned short* __restrict__ wf,
    const float* __restrict__ bm, const float* __restrict__ bq,
    const float* __restrict__ bk, const float* __restrict__ bv,
    const float* __restrict__ b1, const float* __restrict__ b2,
    const float* __restrict__ bmean, const float* __restrict__ bval,
    float* __restrict__ out)          // mean [32768][2] then val [32768]
{
    __shared__ __align__(16) short U[28672];

    const int tid  = threadIdx.x;
    const int wv   = tid >> 6;
    const int lane = tid & 63;
    const int l15  = lane & 15;
    const int q    = lane >> 4;
    const int seqbase = (blockIdx.x * 4 + wv) * 16;   // 16 seqs = 2 batches
    const f32x4 zz = {0.f, 0.f, 0.f, 0.f};

    const float sc_rz = -LOG2E;
    const float sc_n  = 2.0f * LOG2E;

    // ---- x-frag table fill (768 lane-rows / 256 threads) ----
    for (int it = 0; it < 3; ++it) {
        int row = it * 256 + tid;          // 0..767
        int f = row >> 6, ln = row & 63;
        int l = ln & 15, qq = ln >> 4;
        short v[8] = {0,0,0,0,0,0,0,0};
        if (qq == 0) {
            float s = (f < 8) ? sc_rz : sc_n;
            int g = f * 16 + l;            // f=8..11 -> g=128..191 (n-gate rows)
            #pragma unroll
            for (int u = 0; u < 4; ++u) v[u] = f2bf(W_ih[g * 4 + u] * s);
            v[4] = f2bf(((f < 8) ? (b_ih[g] + b_hh[g]) : b_ih[g]) * s);
        }
        *(bf16x8*)&U[row * 8] = *(bf16x8*)v;
    }

    // ---- W_hh A-frags in registers (24 frags = 96 regs, acc-file eligible) ----
    bf16x8 Wh[24];
    #pragma unroll
    for (int f = 0; f < 24; ++f) {
        int jg = f >> 1, c = f & 1;
        float s = (jg < 8) ? sc_rz : sc_n;
        const float* wp = W_hh + (jg * 16 + l15) * 64 + c * 32 + q * 8;
        bf16x8 w;
        #pragma unroll
        for (int u = 0; u < 8; ++u) w[u] = f2bf(wp[u] * s);
        Wh[f] = w;
    }
    // b_hh_n per-lane consts: C elem (jt,r) -> n-row 128 + jt*16 + q*4 + r
    float bhh[4][4];
    #pragma unroll
    for (int jt = 0; jt < 4; ++jt)
        #pragma unroll
        for (int r = 0; r < 4; ++r)
            bhh[jt][r] = b_hh[128 + jt * 16 + q * 4 + r] * sc_n;

    __syncthreads();

    // ---- GRU main loop: h^T in packed registers ----
    // Lane (l15,q): h[jt][r] = h-dim (jt*16 + q*4 + r) of seq l15.
    unsigned Ph[4][2] = {{0u,0u},{0u,0u},{0u,0u},{0u,0u}};
    float h[4][4];
    #pragma unroll
    for (int jt = 0; jt < 4; ++jt)
        #pragma unroll
        for (int r = 0; r < 4; ++r) h[jt][r] = 0.f;

    const int srcA = (((lane >> 4) & 1) * 32 + l15) * 4;   // bpermute byte addr
    const int srcB = srcA + 64;
    // Branch-proof select mask: -1 for q<2, 0 for q>=2. Arithmetic (no compare),
    // laundered so the compiler cannot trace it to a condition and form a branch.
    const int selmask = launder((q >> 1) - 1);
    const float* myseq = seq + (size_t)(seqbase + l15) * 256;

#define LDX(f) (*(const bf16x8*)(Wb + (f) * 512))
#define BP(a, v) __builtin_amdgcn_ds_bpermute((a), (int)(v))

    // FULL-EXEC pull of one h chunk. All 8 bpermutes unconditional; result
    // merge is bitwise (v_bfi) — if-conversion impossible (the R8/R10 bug).
    auto pull = [&](const unsigned* Plo, const unsigned* Phi) -> bf16x8 {
        int aL0 = BP(srcA, Plo[0]), aL1 = BP(srcA, Plo[1]);
        int bL0 = BP(srcB, Plo[0]), bL1 = BP(srcB, Plo[1]);
        int aH0 = BP(srcA, Phi[0]), aH1 = BP(srcA, Phi[1]);
        int bH0 = BP(srcB, Phi[0]), bH1 = BP(srcB, Phi[1]);
        i4h8 u;
        u.i[0] = (aL0 & selmask) | (aH0 & ~selmask);
        u.i[1] = (aL1 & selmask) | (aH1 & ~selmask);
        u.i[2] = (bL0 & selmask) | (bH0 & ~selmask);
        u.i[3] = (bL1 & selmask) | (bH1 & ~selmask);
        return u.h;
    };

    f32x4 xc = *(const f32x4*)myseq;

    for (int t = 0; t < 64; ++t) {
        int tn = (t < 63) ? t + 1 : 63;
        f32x4 xnext = *(const f32x4*)(myseq + tn * 4);

        const short* Wb = U + launder(lane * 8);   // re-laundered per step (no LICM)

        // x B-frag: k0..3 = x, k4 = 1.0 (bias col), q!=0 lanes zero
        i4h8 xb;
        unsigned xu0 = packbf(xc[0], xc[1]);
        unsigned xu1 = packbf(xc[2], xc[3]);
        int qm = launder(((q + 63) >> 6) - 1);     // -1 iff q==0, else 0 (branch-proof)
        xb.i[0] = (int)xu0 & qm;
        xb.i[1] = (int)xu1 & qm;
        xb.i[2] = 0x00003f80 & qm;
        xb.i[3] = 0;
        bf16x8 xB = xb.h;

        // h B-frags via full-exec cross-lane pulls
        bf16x8 Bh0 = pull(Ph[0], Ph[1]);   // h dims 0..31
        bf16x8 Bh1 = pull(Ph[2], Ph[3]);   // h dims 32..63

        #pragma unroll
        for (int jt = 0; jt < 4; ++jt) {
            f32x4 ar = MFMA16(LDX(jt), xB, zz, 0, 0, 0);
            ar = MFMA16(Wh[jt * 2],     Bh0, ar, 0, 0, 0);
            ar = MFMA16(Wh[jt * 2 + 1], Bh1, ar, 0, 0, 0);
            f32x4 az = MFMA16(LDX(4 + jt), xB, zz, 0, 0, 0);
            az = MFMA16(Wh[8 + jt * 2],     Bh0, az, 0, 0, 0);
            az = MFMA16(Wh[8 + jt * 2 + 1], Bh1, az, 0, 0, 0);
            f32x4 an = MFMA16(Wh[16 + jt * 2],     Bh0, zz, 0, 0, 0);
            an = MFMA16(Wh[16 + jt * 2 + 1], Bh1, an, 0, 0, 0);
            f32x4 ax = MFMA16(LDX(8 + jt), xB, zz, 0, 0, 0);

            #pragma unroll
            for (int r = 0; r < 4; ++r) {
                float e_r  = fexp2(ar[r]);                 // exp(-pre_r)
                float rg   = frcp(1.f + e_r);
                float e_z  = fexp2(az[r]);                 // exp(-pre_z)
                float anb  = an[r] + bhh[jt][r];           // 2log2e * hn
                float npre = fmaf(rg, anb, ax[r]);         // 2log2e*(xn + r*hn)
                float e_t  = fexp2(npre);
                float tp   = e_t + 1.f;
                float tm   = e_t - 1.f;
                float hv   = h[jt][r];
                float num  = fmaf(hv, tp, e_z * tm);
                float den  = fmaf(tp, e_z, tp);
                h[jt][r] = num * frcp(den);
            }
            Ph[jt][0] = packbf(h[jt][0], h[jt][1]);
            Ph[jt][1] = packbf(h[jt][2], h[jt][3]);
        }
        xc = xnext;
    }

    // final hcat frags: B[k=dim][n=seq] lane layout == A[m=seq][k=dim]
    bf16x8 Hc0 = pull(Ph[0], Ph[1]);
    bf16x8 Hc1 = pull(Ph[2], Ph[3]);
#undef LDX
#undef BP

    __syncthreads();   // x-table dead; re-purpose LDS for head buffers

    // ---- head buffers (alias LDS) ----
    short (*R1)[136] = (short(*)[136])(U + wv * 7168);
    short (*R2)[136] = (short(*)[136])(U + wv * 7168 + 2176);
    short (*R3)[136] = (short(*)[136])(U + wv * 7168 + 4352);
    short (*Pb)[40]  = (short(*)[40]) (U + wv * 7168 + 6528);

    *(bf16x8*)&R1[l15][q * 8]      = Hc0;   // h cols 0..31
    *(bf16x8*)&R1[l15][32 + q * 8] = Hc1;   // h cols 32..63
    {   // id embedding -> R1 cols 64..79 (agent row i uses embed[i&7])
        const float* ep = embed + (l15 & 7) * 16 + q * 4;
        #pragma unroll
        for (int u = 0; u < 4; ++u) R1[l15][64 + q * 4 + u] = f2bf(ep[u]);
    }
    const bf16x8 z8 = {0,0,0,0,0,0,0,0};
    if (q < 2) {   // zero pad cols 112..127 (K=128 MFMA reads)
        *(bf16x8*)&R1[l15][112 + q * 8] = z8;
        *(bf16x8*)&R2[l15][112 + q * 8] = z8;
        *(bf16x8*)&R3[l15][112 + q * 8] = z8;
    }
    if (q < 3) *(bf16x8*)&Pb[l15][16 + q * 8] = z8;   // zero Pb cols 16..39
    lds_fence();

    auto ld = [&](int fid) -> bf16x8 {
        return *(const bf16x8*)(wf + ((size_t)fid * 64 + lane) * 8);
    };

    // P1+P2: msgs = [h|id] @ Wm^T ; comm mean over own batch; c -> R1 cols 80..111
    #pragma unroll
    for (int ct = 0; ct < 2; ++ct) {
        f32x4 acc = zz;
        #pragma unroll
        for (int ch = 0; ch < 3; ++ch) {
            bf16x8 a = *(const bf16x8*)&R1[l15][ch * 32 + q * 8];
            acc = MFMA16(a, ld(ct * 3 + ch), acc, 0, 0, 0);
        }
        float s = acc[0] + acc[1] + acc[2] + acc[3];   // rows q*4..q*4+3
        s += __shfl_xor(s, 16, 64);                    // + other q of same batch
        float cv = 0.125f * s + bm[16 * ct + l15];
        short cb = f2bf_hu(cv);
        #pragma unroll
        for (int r = 0; r < 4; ++r) R1[q * 4 + r][80 + 16 * ct + l15] = cb;
    }
    lds_fence();

    // P3: Q -> R2, K -> R3 (K=112 pad 128); Q pre-scaled by 1/sqrt(112)
    #pragma unroll
    for (int ct = 0; ct < 7; ++ct) {
        f32x4 aq = zz, ak = zz;
        #pragma unroll
        for (int ch = 0; ch < 4; ++ch) {
            bf16x8 a = *(const bf16x8*)&R1[l15][ch * 32 + q * 8];
            aq = MFMA16(a, ld(6  + ct * 4 + ch), aq, 0, 0, 0);
            ak = MFMA16(a, ld(34 + ct * 4 + ch), ak, 0, 0, 0);
        }
        int col = 16 * ct + l15;
        float biq = bq[col], bik = bk[col];
        #pragma unroll
        for (int r = 0; r < 4; ++r) {
            int row = q * 4 + r;
            R2[row][col] = f2bf_hu((aq[r] + biq) * INV_SQRT_D);
            R3[row][col] = f2bf_hu(ak[r] + bik);
        }
    }
    lds_fence();

    // P4: S = Q K^T (16x16 = 2 batches block-diagonal); 8-wide softmax via shfl
    {
        f32x4 acc = zz;
        #pragma unroll
        for (int ch = 0; ch < 4; ++ch) {
            bf16x8 a = *(const bf16x8*)&R2[l15][ch * 32 + q * 8];
            bf16x8 b = *(const bf16x8*)&R3[l15][ch * 32 + q * 8];
            acc = MFMA16(a, b, acc, 0, 0, 0);
        }
        bool collow = (l15 < 8);
        #pragma unroll
        for (int r = 0; r < 4; ++r) {
            int rl = q * 4 + r;
            bool valid = ((rl < 8) == collow);
            float v = acc[r];
            float m = v;
            m = fmaxf(m, __shfl_xor(m, 1, 64));
            m = fmaxf(m, __shfl_xor(m, 2, 64));
            m = fmaxf(m, __shfl_xor(m, 4, 64));
            float e = fexp2(LOG2E * (v - m));
            float s = e;
            s += __shfl_xor(s, 1, 64);
            s += __shfl_xor(s, 2, 64);
            s += __shfl_xor(s, 4, 64);
            float pv = valid ? e * frcp(s) : 0.f;
            Pb[rl][l15] = f2bf_hu(pv);
        }
    }
    lds_fence();

    // P5a: V-pass (hcat in R1 still live) -> V^T overlay in R2 [112][18] (Q dead)
    {
        short* VtR = &R2[0][0];
        #pragma unroll
        for (int ct = 0; ct < 7; ++ct) {
            f32x4 av = zz;
            #pragma unroll
            for (int ch = 0; ch < 4; ++ch) {
                bf16x8 a = *(const bf16x8*)&R1[l15][ch * 32 + q * 8];
                av = MFMA16(a, ld(62 + ct * 4 + ch), av, 0, 0, 0);
            }
            int col = 16 * ct + l15;
            float biv = bv[col];
            #pragma unroll
            for (int r = 0; r < 4; ++r)
                VtR[col * 18 + q * 4 + r] = f2bf_hu(av[r] + biv);
        }
    }
    lds_fence();

    // P5b: O = P V (K=32; Pb cols 16..31 zero) -> R1
    {
        const short* VtR = &R2[0][0];
        bf16x8 a = *(const bf16x8*)&Pb[l15][q * 8];
        #pragma unroll
        for (int ct = 0; ct < 7; ++ct) {
            bf16x8 b = *(const bf16x8*)(VtR + (16 * ct + l15) * 18 + q * 8);
            f32x4 acc = MFMA16(a, b, zz, 0, 0, 0);
            #pragma unroll
            for (int r = 0; r < 4; ++r) R1[q * 4 + r][16 * ct + l15] = f2bf_hu(acc[r]);
        }
    }
    lds_fence();

    // P6: h3 = relu(O @ W1^T + b1)  K=112 pad 128 -> R2 (Vt dead; all cols written)
    #pragma unroll
    for (int ct = 0; ct < 8; ++ct) {
        f32x4 acc = zz;
        #pragma unroll
        for (int ch = 0; ch < 4; ++ch) {
            bf16x8 a = *(const bf16x8*)&R1[l15][ch * 32 + q * 8];
            acc = MFMA16(a, ld(90 + ct * 4 + ch), acc, 0, 0, 0);
        }
        float bias = b1[16 * ct + l15];
        #pragma unroll
        for (int r = 0; r < 4; ++r)
            R2[q * 4 + r][16 * ct + l15] = f2bf_hu(fmaxf(acc[r] + bias, 0.f));
    }
    lds_fence();

    // P7: h4 = relu(h3 @ W2^T + b2)  K=128 -> R3
    #pragma unroll
    for (int ct = 0; ct < 8; ++ct) {
        f32x4 acc = zz;
        #pragma unroll
        for (int ch = 0; ch < 4; ++ch) {
            bf16x8 a = *(const bf16x8*)&R2[l15][ch * 32 + q * 8];
            acc = MFMA16(a, ld(122 + ct * 4 + ch), acc, 0, 0, 0);
        }
        float bias = b2[16 * ct + l15];
        #pragma unroll
        for (int r = 0; r < 4; ++r)
            R3[q * 4 + r][16 * ct + l15] = f2bf_hu(fmaxf(acc[r] + bias, 0.f));
    }
    lds_fence();

    // P8: heads (K=128): cols 0,1 -> mean; col 2 -> value
    {
        f32x4 acc = zz;
        #pragma unroll
        for (int ch = 0; ch < 4; ++ch) {
            bf16x8 a = *(const bf16x8*)&R3[l15][ch * 32 + q * 8];
            acc = MFMA16(a, ld(154 + ch), acc, 0, 0, 0);
        }
        if (l15 < 3) {
            float bias = (l15 == 0) ? bmean[0] : (l15 == 1) ? bmean[1] : bval[0];
            #pragma unroll
            for (int r = 0; r < 4; ++r) {
                int A = seqbase + q * 4 + r;
                float v = acc[r] + bias;
                if (l15 < 2) out[(size_t)A * 2 + l15] = v;
                else         out[65536 + A] = v;
            }
        }
    }
}

// ---------------------------------------------------------------------------
extern "C" void kernel_launch(void* const* d_in, const int* in_sizes, int n_in,
                              void* d_out, int out_size, void* d_ws, size_t ws_size,
                              hipStream_t stream) {
    const float* seq   = (const float*)d_in[0];
    const float* W_ih  = (const float*)d_in[1];
    const float* W_hh  = (const float*)d_in[2];
    const float* b_ih  = (const float*)d_in[3];
    const float* b_hh  = (const float*)d_in[4];
    const float* embed = (const float*)d_in[5];
    const float* Wm    = (const float*)d_in[6];
    const float* bm    = (const float*)d_in[7];
    const float* Wq    = (const float*)d_in[8];
    const float* bq    = (const float*)d_in[9];
    const float* Wk    = (const float*)d_in[10];
    const float* bk    = (const float*)d_in[11];
    const float* Wv    = (const float*)d_in[12];
    const float* bv    = (const float*)d_in[13];
    const float* W1    = (const float*)d_in[14];
    const float* b1    = (const float*)d_in[15];
    const float* W2    = (const float*)d_in[16];
    const float* b2    = (const float*)d_in[17];
    const float* Wmean = (const float*)d_in[18];
    const float* bmean = (const float*)d_in[19];
    const float* Wval  = (const float*)d_in[20];
    const float* bval  = (const float*)d_in[21];

    unsigned short* wf = (unsigned short*)d_ws;   // 158 frags * 64 lanes * 16 B

    conv_kernel<<<40, 256, 0, stream>>>(Wm, Wq, Wk, Wv, W1, W2, Wmean, Wval, wf);
    policy_kernel<<<512, 256, 0, stream>>>(seq, W_ih, W_hh, b_ih, b_hh, embed, wf,
                                           bm, bq, bk, bv, b1, b2, bmean, bval,
                                           (float*)d_out);
}